// Round 1
// baseline (207.683 us; speedup 1.0000x reference)
//
#include <hip/hip_runtime.h>
#include <cstdint>
#include <cstddef>

// Shapes fixed by the reference harness.
#define MM 2048
#define KK 4096
#define NN 4096
#define GG 32   // K / 128 groups
#define BM 128
#define BN 256
#define BK 64
#define NTILES (KK / BK)   // 64 k-tiles

typedef _Float16 half8_t __attribute__((ext_vector_type(8)));
typedef _Float16 half4_t __attribute__((ext_vector_type(4)));
typedef float f32x4 __attribute__((ext_vector_type(4)));

__device__ __forceinline__ void load_lds16(const void* gptr, void* lptr) {
  // 16B-per-lane direct global->LDS (emits global_load_lds_dwordx4).
  // LDS dest = wave-uniform base + lane*16 (NOT a per-lane scatter).
  __builtin_amdgcn_global_load_lds(
      (const __attribute__((address_space(1))) unsigned int*)gptr,
      (__attribute__((address_space(3))) unsigned int*)lptr, 16, 0, 0);
}

// Merged prep: first MM*KK/8 threads convert A fp32->fp16; the rest dequant
// qweight -> fp16 via w = fma(q, s, -z*s). 8 elements/thread: 2x16B loads,
// 1x16B store (R7: was 4/thread with 8B stores). Block-uniform branch.
#define ACNT8 (MM * KK / 8)   // 1M half8-threads for A
__global__ void prep_kernel(const float* __restrict__ A, const int* __restrict__ q,
                            const float* __restrict__ scales, const float* __restrict__ zeros,
                            _Float16* __restrict__ Ah, _Float16* __restrict__ Wh) {
  const int i = blockIdx.x * blockDim.x + threadIdx.x;
  if (i < ACNT8) {
    const float4 v0 = ((const float4*)A)[2 * (size_t)i];
    const float4 v1 = ((const float4*)A)[2 * (size_t)i + 1];
    half8_t h;
    h[0] = (_Float16)v0.x; h[1] = (_Float16)v0.y; h[2] = (_Float16)v0.z; h[3] = (_Float16)v0.w;
    h[4] = (_Float16)v1.x; h[5] = (_Float16)v1.y; h[6] = (_Float16)v1.z; h[7] = (_Float16)v1.w;
    *(half8_t*)(Ah + 8 * (size_t)i) = h;
  } else {
    const int j = i - ACNT8;
    const int e = j << 3;         // element index, < 16.8M fits int
    const int n = e >> 12;        // / KK
    const int k = e & (KK - 1);
    const int g = k >> 7;         // / 128 (8 consecutive k share a group)
    const float sc = scales[(n << 5) + g];
    const float zp = zeros[(n << 5) + g];
    const float nzs = -zp * sc;
    const int4 q0 = ((const int4*)q)[2 * (size_t)j];
    const int4 q1 = ((const int4*)q)[2 * (size_t)j + 1];
    half8_t h;
    h[0] = (_Float16)fmaf((float)q0.x, sc, nzs);
    h[1] = (_Float16)fmaf((float)q0.y, sc, nzs);
    h[2] = (_Float16)fmaf((float)q0.z, sc, nzs);
    h[3] = (_Float16)fmaf((float)q0.w, sc, nzs);
    h[4] = (_Float16)fmaf((float)q1.x, sc, nzs);
    h[5] = (_Float16)fmaf((float)q1.y, sc, nzs);
    h[6] = (_Float16)fmaf((float)q1.z, sc, nzs);
    h[7] = (_Float16)fmaf((float)q1.w, sc, nzs);
    *(half8_t*)(Wh + (size_t)e) = h;
  }
}

// ---------------------------------------------------------------------------
// R7 main GEMM: phase-split schedule with counted vmcnt (T3+T4) + setprio (T5).
// 128x256 tile, BK=64, 512 threads = 8 waves (2x4), 64x64 out per wave
// (4x4 frags of 16x16x32 f16 MFMA). Grid 16x16 = 256 blocks = 1/CU.
//
// Pipeline: 3 LDS buffers (144 KiB), prefetch distance 2. While computing
// tile t from buf[t%3], the 6 global_load_lds for tile t+2 are issued into
// buf[(t+2)%3] (last read during tile t-1, so safe to overwrite). Tile
// boundary waits s_waitcnt vmcnt(6) -- tile t+1's loads complete, t+2's 6
// stay IN FLIGHT across the barrier (never drain to 0 in steady state;
// this is the whole point vs. the old __syncthreads() structure).
//
// Per tile, 2 phases (mi 0..1 then mi 2..3), each:
//   ds_read subtile (12 resp. 4 x ds_read_b128)  -- from buf[cur]
//   issue 3 staging loads for tile t+2           -- into buf[nb]
//   sched_barrier(0); s_barrier                  -- raw, no vmcnt drain
//   setprio(1); 16 MFMA; setprio(0); s_barrier
//
// LDS swizzle carried over from the verified kernel (bank conflicts = 0):
// physical 16B chunk p at row r holds global chunk p ^ (r&7); staging
// pre-swizzles the per-lane GLOBAL address (gchunk = (lane&7) ^ (lane>>3)),
// reads use j ^ (lr&7). Row-of-8 alignment makes row&7 == lane>>3 == lr&7.
// ---------------------------------------------------------------------------
__global__ __launch_bounds__(512, 2)
void gemm8_kernel(const _Float16* __restrict__ Ah, const _Float16* __restrict__ Wh,
                  const float* __restrict__ bias, float* __restrict__ out)
{
  __shared__ __align__(16) _Float16 sA[3][BM * BK];   // 3 x 16 KiB
  __shared__ __align__(16) _Float16 sB[3][BN * BK];   // 3 x 32 KiB

  const int tid = threadIdx.x;
  const int lane = tid & 63;
  const int wave = tid >> 6;        // 0..7
  const int wr = wave >> 2;         // 0..1  (m-row of wave)
  const int wc = wave & 3;          // 0..3  (n-col of wave)
  const int lr = lane & 15, quad = lane >> 4;

  // XCD-aware swizzle: 256 blocks, 8 XCDs round-robin by bid. Each XCD owns
  // 2 n-tile columns; per-K-step XCD working set = full A slice (256KB) +
  // 2 B panels (64KB) -> fits 4MB per-XCD L2.
  const int bid = blockIdx.x;
  const int xcd = bid & 7;
  const int slot = bid >> 3;        // 0..31
  const int mt = slot >> 1;         // 0..15
  const int nt = xcd * 2 + (slot & 1);
  const int m0 = mt * BM;
  const int n0 = nt * BN;

  // staging geometry: per instr a wave covers 8 rows x 64 halves (1 KiB
  // linear LDS); lane l -> row +(l>>3), physical chunk l&7, global chunk
  // (l&7)^(l>>3).
  const int srow = lane >> 3, scc = lane & 7, gch = scc ^ srow;

  f32x4 acc[4][4];
#pragma unroll
  for (int i = 0; i < 4; ++i)
#pragma unroll
    for (int j = 0; j < 4; ++j) acc[i][j] = (f32x4){0.f, 0.f, 0.f, 0.f};

  auto stageA = [&](int t, int buf, int i) {   // i in {0,1}: rows i*64..i*64+63
    load_lds16(Ah + (size_t)(m0 + i * 64 + (wave << 3) + srow) * KK + t * BK + (gch << 3),
               (void*)&sA[buf][(i * 64 + (wave << 3)) * BK]);
  };
  auto stageB = [&](int t, int buf, int i) {   // i in {0..3}: rows i*64..i*64+63
    load_lds16(Wh + (size_t)(n0 + i * 64 + (wave << 3) + srow) * KK + t * BK + (gch << 3),
               (void*)&sB[buf][(i * 64 + (wave << 3)) * BK]);
  };

  // Prologue: stage tiles 0 and 1 (6 loads each, same issue order as loop).
  stageB(0, 0, 0); stageB(0, 0, 1); stageA(0, 0, 0);
  stageB(0, 0, 2); stageB(0, 0, 3); stageA(0, 0, 1);
  stageB(1, 1, 0); stageB(1, 1, 1); stageA(1, 1, 0);
  stageB(1, 1, 2); stageB(1, 1, 3); stageA(1, 1, 1);
  asm volatile("s_waitcnt vmcnt(6)" ::: "memory");   // tile 0 landed, tile 1 in flight
  __builtin_amdgcn_s_barrier();

  int cur = 0, nb = 2;
  for (int t = 0; t < NTILES; ++t) {
    const _Float16* pA = sA[cur];
    const _Float16* pB = sB[cur];
    const bool st = (t < NTILES - 2);   // uniform
    half8_t a0[2][2], a1[2][2], b[4][2];

    // ---- phase 0: mi 0..1, all ni ----
#pragma unroll
    for (int x = 0; x < 2; ++x) {
      const _Float16* ba = &pA[(wr * 64 + x * 16 + lr) * BK];
#pragma unroll
      for (int ks = 0; ks < 2; ++ks)
        a0[x][ks] = *(const half8_t*)&ba[((ks * 4 + quad) ^ (lr & 7)) * 8];
    }
#pragma unroll
    for (int ni = 0; ni < 4; ++ni) {
      const _Float16* bb = &pB[(wc * 64 + ni * 16 + lr) * BK];
#pragma unroll
      for (int ks = 0; ks < 2; ++ks)
        b[ni][ks] = *(const half8_t*)&bb[((ks * 4 + quad) ^ (lr & 7)) * 8];
    }
    if (st) { stageB(t + 2, nb, 0); stageB(t + 2, nb, 1); stageA(t + 2, nb, 0); }
    __builtin_amdgcn_sched_barrier(0);
    __builtin_amdgcn_s_barrier();
    __builtin_amdgcn_s_setprio(1);
#pragma unroll
    for (int x = 0; x < 2; ++x)
#pragma unroll
      for (int ni = 0; ni < 4; ++ni) {
        acc[x][ni] = __builtin_amdgcn_mfma_f32_16x16x32_f16(a0[x][0], b[ni][0], acc[x][ni], 0, 0, 0);
        acc[x][ni] = __builtin_amdgcn_mfma_f32_16x16x32_f16(a0[x][1], b[ni][1], acc[x][ni], 0, 0, 0);
      }
    __builtin_amdgcn_s_setprio(0);
    __builtin_amdgcn_s_barrier();

    // ---- phase 1: mi 2..3, all ni (b[] reused from regs) ----
#pragma unroll
    for (int x = 0; x < 2; ++x) {
      const _Float16* ba = &pA[(wr * 64 + (x + 2) * 16 + lr) * BK];
#pragma unroll
      for (int ks = 0; ks < 2; ++ks)
        a1[x][ks] = *(const half8_t*)&ba[((ks * 4 + quad) ^ (lr & 7)) * 8];
    }
    if (st) { stageB(t + 2, nb, 2); stageB(t + 2, nb, 3); stageA(t + 2, nb, 1); }
    __builtin_amdgcn_sched_barrier(0);
    __builtin_amdgcn_s_barrier();
    __builtin_amdgcn_s_setprio(1);
#pragma unroll
    for (int x = 0; x < 2; ++x)
#pragma unroll
      for (int ni = 0; ni < 4; ++ni) {
        acc[x + 2][ni] = __builtin_amdgcn_mfma_f32_16x16x32_f16(a1[x][0], b[ni][0], acc[x + 2][ni], 0, 0, 0);
        acc[x + 2][ni] = __builtin_amdgcn_mfma_f32_16x16x32_f16(a1[x][1], b[ni][1], acc[x + 2][ni], 0, 0, 0);
      }
    __builtin_amdgcn_s_setprio(0);
    // Tile boundary: tile t+1 must have landed; tile t+2's 6 loads stay in
    // flight (counted vmcnt -- never 0 until the epilogue tiles).
    if (t < NTILES - 2) asm volatile("s_waitcnt vmcnt(6)" ::: "memory");
    else                asm volatile("s_waitcnt vmcnt(0)" ::: "memory");
    __builtin_amdgcn_s_barrier();
    cur = (cur == 2) ? 0 : cur + 1;
    nb  = (nb  == 2) ? 0 : nb + 1;
  }

  // Epilogue. C/D layout (verified, dtype-independent): col = lane&15,
  // row = quad*4 + reg.
#pragma unroll
  for (int ni = 0; ni < 4; ++ni) {
    const int n = n0 + wc * 64 + ni * 16 + lr;
    const float bv = bias[n];
#pragma unroll
    for (int mi = 0; mi < 4; ++mi) {
      const int mbase = m0 + wr * 64 + mi * 16 + quad * 4;
#pragma unroll
      for (int r = 0; r < 4; ++r)
        out[(size_t)(mbase + r) * NN + n] = acc[mi][ni][r] + bv;
    }
  }
}

// Fallback (ws too small): the previous verified 128x128 fused-dequant kernel,
// reg-staged with inline convert/dequant. Unchanged.
__global__ __launch_bounds__(256, 2)
void gemm_fused_kernel(const float* __restrict__ Af, const int* __restrict__ qw,
                       const float* __restrict__ scales, const float* __restrict__ zeros,
                       const float* __restrict__ bias, float* __restrict__ out)
{
  __shared__ __align__(16) _Float16 sA[128 * 64];
  __shared__ __align__(16) _Float16 sB[128 * 64];

  const int tid = threadIdx.x;
  const int lane = tid & 63;
  const int wave = tid >> 6;
  const int wr = wave >> 1, wc = wave & 1;

  const int bid = blockIdx.x;
  const int xcd = bid & 7;
  const int slot = bid >> 3;
  const int mt = slot >> 2;
  const int nt = xcd * 4 + (slot & 3);
  const int m0 = mt * 128;
  const int n0 = nt * 128;

  const int lr = lane & 15, quad = lane >> 4;

  f32x4 acc[4][4];
#pragma unroll
  for (int i = 0; i < 4; ++i)
#pragma unroll
    for (int j = 0; j < 4; ++j) acc[i][j] = (f32x4){0.f, 0.f, 0.f, 0.f};

  const int frow = tid >> 4;
  const int fc4 = tid & 15;

  for (int kt = 0; kt < KK / 64; ++kt) {
    const int k0 = kt * 64;
    const int g = k0 >> 7;
#pragma unroll
    for (int p = 0; p < 8; ++p) {
      const int row = p * 16 + frow;
      const int pc = (fc4 >> 1) ^ (row & 7);
      const int dst = row * 64 + pc * 8 + (fc4 & 1) * 4;
      const float4 avf = *(const float4*)&Af[(size_t)(m0 + row) * KK + k0 + fc4 * 4];
      half4_t ah;
      ah[0] = (_Float16)avf.x; ah[1] = (_Float16)avf.y;
      ah[2] = (_Float16)avf.z; ah[3] = (_Float16)avf.w;
      *(half4_t*)&sA[dst] = ah;
      const int n = n0 + row;
      const float sc = scales[(n << 5) + g];
      const float zp = zeros[(n << 5) + g];
      const float nzs = -zp * sc;
      const int4 qv = *(const int4*)&qw[(size_t)n * KK + k0 + fc4 * 4];
      half4_t bh;
      bh[0] = (_Float16)fmaf((float)qv.x, sc, nzs);
      bh[1] = (_Float16)fmaf((float)qv.y, sc, nzs);
      bh[2] = (_Float16)fmaf((float)qv.z, sc, nzs);
      bh[3] = (_Float16)fmaf((float)qv.w, sc, nzs);
      *(half4_t*)&sB[dst] = bh;
    }
    __syncthreads();
#pragma unroll
    for (int ks = 0; ks < 2; ++ks) {
      half8_t a[4], b[4];
#pragma unroll
      for (int t = 0; t < 4; ++t) {
        const int rA = wr * 64 + t * 16 + lr;
        const int j = ks * 4 + quad;
        a[t] = *(const half8_t*)&sA[rA * 64 + ((j ^ (lr & 7)) * 8)];
        const int rB = wc * 64 + t * 16 + lr;
        b[t] = *(const half8_t*)&sB[rB * 64 + ((j ^ (lr & 7)) * 8)];
      }
#pragma unroll
      for (int mi = 0; mi < 4; ++mi)
#pragma unroll
        for (int ni = 0; ni < 4; ++ni)
          acc[mi][ni] = __builtin_amdgcn_mfma_f32_16x16x32_f16(a[mi], b[ni], acc[mi][ni], 0, 0, 0);
    }
    __syncthreads();
  }

#pragma unroll
  for (int ni = 0; ni < 4; ++ni) {
    const int n = n0 + wc * 64 + ni * 16 + lr;
    const float bv = bias[n];
#pragma unroll
    for (int mi = 0; mi < 4; ++mi) {
      const int mbase = m0 + wr * 64 + mi * 16 + quad * 4;
#pragma unroll
      for (int r = 0; r < 4; ++r)
        out[(size_t)(mbase + r) * NN + n] = acc[mi][ni][r] + bv;
    }
  }
}

extern "C" void kernel_launch(void* const* d_in, const int* in_sizes, int n_in,
                              void* d_out, int out_size, void* d_ws, size_t ws_size,
                              hipStream_t stream) {
  (void)in_sizes; (void)n_in; (void)out_size;
  const float* A      = (const float*)d_in[0];
  const int*   qw     = (const int*)d_in[1];
  const float* scales = (const float*)d_in[2];
  const float* zeros  = (const float*)d_in[3];
  const float* bias   = (const float*)d_in[4];
  float* out = (float*)d_out;

  const size_t needA = (size_t)MM * KK * sizeof(_Float16);  // 16 MB
  const size_t needW = (size_t)NN * KK * sizeof(_Float16);  // 32 MB

  if (ws_size >= needA + needW) {
    _Float16* Ah = (_Float16*)d_ws;
    _Float16* Wh = (_Float16*)((char*)d_ws + needA);
    prep_kernel<<<((MM + NN) * KK / 8) / 256, 256, 0, stream>>>(A, qw, scales, zeros, Ah, Wh);
    gemm8_kernel<<<dim3(MM / BM * NN / BN), dim3(512), 0, stream>>>(Ah, Wh, bias, out);
  } else {
    gemm_fused_kernel<<<dim3(512), dim3(256), 0, stream>>>(A, qw, scales, zeros, bias, out);
  }
}